// Round 13
// baseline (850.758 us; speedup 1.0000x reference)
//
#include <hip/hip_runtime.h>
#include <stdint.h>

// ---------------------------------------------------------------------------
// SelfAttention: out[b,n,d] = ( softmax( (X^T Wk)(X^T Wq)^T / 32 ) (X^T Wv) )^T
// B=16, N=D=1024.
//
// R5 algebra: kq = xT (Wk Wq^T) x -> 4 big GEMMs (tmp, vvT, kq(P), out).
// R6a fusion: softmax folded into GEMM epilogues (EPI=2 exp+Spart, EPI=3 /S).
// R7 gemm: 256x128 tile, BK=64, 512thr/8 waves, 48KiB LDS (P/out keep this).
// R11/R14: pair merge + prep consolidation -> 276.2 us best.
// R15 post-mortem: producer-consumer P/out merge regressed (sleeping
//   consumers hold residency slots -> producers at ~1 block/CU).  Closed.
// R16 (this): revert to R14 everywhere EXCEPT gemm_pair, which moves to a
//   256x256 tile (2M x 4N waves, wave-tile 128x64, acc[8][4], single-buffer
//   64KB LDS).  LDS-read bytes/flop: 0.0305 -> 0.0229 (-25%); pair grid
//   2x256=512 blocks = 2/CU (fits: 64KB x 2 <= 160KB).  P/out stay 256x128
//   (256-block grids at 256^2 would be 1/CU).  Rationale: pair's +17% at
//   3/CU proved the LDS pipe is NOT saturated at 2/CU (drain gaps), so
//   cutting LDS bytes/flop is the remaining lever.
// ---------------------------------------------------------------------------

typedef __bf16 bf16x8_t __attribute__((ext_vector_type(8)));
typedef float  f32x4_t  __attribute__((ext_vector_type(4)));

typedef __attribute__((address_space(3))) uint32_t as3_u32;
typedef __attribute__((address_space(1))) uint32_t as1_u32;

__device__ __forceinline__ void async_copy16(const void* g, const void* l) {
  __builtin_amdgcn_global_load_lds((const as1_u32*)(uintptr_t)g,
                                   (as3_u32*)(uint32_t)(uintptr_t)l,
                                   16, 0, 0);
}

__device__ __forceinline__ uint16_t f2bf(float f) {  // RNE
  uint32_t x = __float_as_uint(f);
  return (uint16_t)((x + 0x7fffu + ((x >> 16) & 1u)) >> 16);
}
__device__ __forceinline__ float bf2f(uint16_t b) {
  return __uint_as_float(((uint32_t)b) << 16);
}

// ---------------- 256x128 body (P and out gemms; R7-proven) ----------------
// C[m,n] = alpha * sum_k A[m,k] * B[n,k].  M=N=K=1024 fixed per batch slice.
// EPI: 2 = bf16 exp(C*alpha) + Spart row partials;
//      3 = f32 C*alpha/S[col] (S = sum of 16 Spart slots).
template <int EPI>
__device__ __forceinline__ void gemm_body(
    const uint16_t* __restrict__ A, const uint16_t* __restrict__ B,
    void* __restrict__ Cv, size_t sA, size_t sB, size_t sC,
    float alpha, float* __restrict__ Sp, int lid, char* smem)
{
  char* As = smem;            // 256 x 64 bf16 = 32768 B
  char* Bs = smem + 32768;    // 128 x 64 bf16 = 16384 B

  const int xcd  = lid & 7;
  const int slot = lid >> 3;            // 0..63
  const int z    = (xcd << 1) | (slot >> 5);
  const int t32  = slot & 31;
  const int bm0  = (t32 >> 3) << 8;     // 0,256,512,768
  const int bn0  = (t32 & 7) << 7;      // 0..896 step 128

  A += (size_t)z * sA + ((size_t)bm0 << 10);
  B += (size_t)z * sB + ((size_t)bn0 << 10);

  const int t    = threadIdx.x;
  const int lane = t & 63;
  const int w    = t >> 6;              // 0..7
  const int q    = lane >> 4;
  const int r16  = lane & 15;
  const int wm   = (w >> 1) << 6;       // 0,64,128,192
  const int wn   = (w & 1) << 6;        // 0,64

  const int g0  = t >> 3;               // 0..63
  const int cp  = t & 7;
  const int ce  = (cp ^ (g0 & 7)) << 3;
  const int so  = (g0 << 7) + (cp << 4);
  const uint16_t* Ag = A + ((size_t)g0 << 10) + ce;
  const uint16_t* Bg = B + ((size_t)g0 << 10) + ce;

  f32x4_t acc[4][4];
#pragma unroll
  for (int i = 0; i < 4; i++)
#pragma unroll
    for (int j = 0; j < 4; j++) acc[i][j] = (f32x4_t){0.f, 0.f, 0.f, 0.f};

  for (int k0 = 0; k0 < 1024; k0 += 64) {
#pragma unroll
    for (int s = 0; s < 4; ++s)
      async_copy16(Ag + (((size_t)s << 6) << 10) + k0, As + so + (s << 13));
#pragma unroll
    for (int s = 0; s < 2; ++s)
      async_copy16(Bg + (((size_t)s << 6) << 10) + k0, Bs + so + (s << 13));
    __syncthreads();

#pragma unroll
    for (int kk = 0; kk < 2; ++kk) {
      bf16x8_t af[4], bfr[4];
#pragma unroll
      for (int mi = 0; mi < 4; ++mi) {
        const int m = wm + (mi << 4) + r16;
        const int c = (kk << 2) + q;
        af[mi] = *(const bf16x8_t*)(As + (m << 7) + ((c ^ (m & 7)) << 4));
      }
#pragma unroll
      for (int ni = 0; ni < 4; ++ni) {
        const int n = wn + (ni << 4) + r16;
        const int c = (kk << 2) + q;
        bfr[ni] = *(const bf16x8_t*)(Bs + (n << 7) + ((c ^ (n & 7)) << 4));
      }
      __builtin_amdgcn_s_setprio(1);
#pragma unroll
      for (int mi = 0; mi < 4; ++mi)
#pragma unroll
        for (int ni = 0; ni < 4; ++ni)
          acc[mi][ni] = __builtin_amdgcn_mfma_f32_16x16x32_bf16(
              af[mi], bfr[ni], acc[mi][ni], 0, 0, 0);
      __builtin_amdgcn_s_setprio(0);
    }
    __syncthreads();
  }

  // ---- epilogue.  C/D layout: col=lane&15, row=q*4+r (verified m89/m91) ----
  if constexpr (EPI == 3) {
    float inv[4];
#pragma unroll
    for (int ni = 0; ni < 4; ++ni) {
      const int c = bn0 + wn + (ni << 4) + r16;
      float S = 0.f;
#pragma unroll
      for (int p = 0; p < 16; ++p)
        S += Sp[((size_t)p << 14) + ((size_t)z << 10) + c];
      inv[ni] = 1.0f / S;
    }
    float* C = (float*)Cv + (size_t)z * sC;
#pragma unroll
    for (int mi = 0; mi < 4; ++mi)
#pragma unroll
      for (int ni = 0; ni < 4; ++ni)
#pragma unroll
        for (int r = 0; r < 4; ++r) {
          const int row = bm0 + wm + (mi << 4) + (q << 2) + r;
          const int col = bn0 + wn + (ni << 4) + r16;
          C[((size_t)row << 10) + col] = acc[mi][ni][r] * alpha * inv[ni];
        }
  } else {
    // EPI==2: bf16 exp() out + per-row partial sums, LDS-staged row stores.
    float* reg = (float*)smem + (size_t)w * 1056;   // 16 x 66 floats
    uint16_t* C = (uint16_t*)Cv + (size_t)z * sC;
    float* SpW = Sp + ((size_t)(((bn0 >> 7) << 1) + (w & 1)) << 14)
                    + ((size_t)z << 10);
#pragma unroll
    for (int mi = 0; mi < 4; ++mi) {
      float ev[4][4];
#pragma unroll
      for (int ni = 0; ni < 4; ++ni)
#pragma unroll
        for (int r = 0; r < 4; ++r) {
          ev[ni][r] = __expf(acc[mi][ni][r] * alpha);
          reg[((q << 2) + r) * 66 + (ni << 4) + r16] = ev[ni][r];
        }
#pragma unroll
      for (int r = 0; r < 4; ++r) {
        float s = ev[0][r] + ev[1][r] + ev[2][r] + ev[3][r];
        s += __shfl_xor(s, 1, 16);
        s += __shfl_xor(s, 2, 16);
        s += __shfl_xor(s, 4, 16);
        s += __shfl_xor(s, 8, 16);
        if (r16 == 0)
          SpW[bm0 + wm + (mi << 4) + (q << 2) + r] = s;
      }
#pragma unroll
      for (int it = 0; it < 8; ++it) {
        const int rr = (it << 1) + (lane >> 5);     // 0..15
        const int cc = (lane & 31) << 1;            // 0..62
        const float2 v = *(const float2*)(reg + rr * 66 + cc);
        const uint32_t p = (uint32_t)f2bf(v.x) | ((uint32_t)f2bf(v.y) << 16);
        const int row = bm0 + wm + (mi << 4) + rr;
        const int col = bn0 + wn + cc;
        *(uint32_t*)(C + ((size_t)row << 10) + col) = p;
      }
    }
  }
}

template <int EPI>
__global__ __launch_bounds__(512, 4)
void gemm_bt256x128(const uint16_t* __restrict__ A,
                    const uint16_t* __restrict__ B,
                    void* __restrict__ Cv, size_t sA, size_t sB, size_t sC,
                    float alpha, float* __restrict__ Sp)
{
  __shared__ __align__(16) char smem[49152];
  gemm_body<EPI>(A, B, Cv, sA, sB, sC, alpha, Sp, blockIdx.x, smem);
}

// ---------------- 256x256 body (pair only): bf16 out, alpha=1 --------------
// Waves 2M x 4N, wave-tile 128x64, acc[8][4].  LDS 64KB single buffer.
// LDS reads/K-tile = 192KB for 8.39 MFLOP (0.0229 B/flop vs 0.0305 at 256x128).
__device__ __forceinline__ void gemm_body256(
    const uint16_t* __restrict__ A, const uint16_t* __restrict__ B,
    uint16_t* __restrict__ Cg, size_t sA, size_t sB, size_t sC,
    int lid, char* smem)
{
  char* As = smem;            // 256 x 64 bf16 = 32768 B
  char* Bs = smem + 32768;    // 256 x 64 bf16 = 32768 B

  // XCD swizzle: lid%8 = XCD; 2 batches per XCD, 4x4 tiles per batch.
  const int xcd  = lid & 7;
  const int slot = lid >> 3;            // 0..31
  const int z    = (xcd << 1) | (slot >> 4);
  const int t16  = slot & 15;
  const int bm0  = (t16 >> 2) << 8;     // 0,256,512,768
  const int bn0  = (t16 & 3) << 8;      // 0,256,512,768

  A += (size_t)z * sA + ((size_t)bm0 << 10);
  B += (size_t)z * sB + ((size_t)bn0 << 10);

  const int t    = threadIdx.x;
  const int lane = t & 63;
  const int w    = t >> 6;              // 0..7
  const int q    = lane >> 4;
  const int r16  = lane & 15;
  const int wm   = (w >> 2) << 7;       // 0,128
  const int wn   = (w & 3) << 6;        // 0,64,128,192

  const int g0  = t >> 3;               // 0..63
  const int cp  = t & 7;
  const int ce  = (cp ^ (g0 & 7)) << 3; // (g0+64s)&7 == g0&7
  const int so  = (g0 << 7) + (cp << 4);
  const uint16_t* Ag = A + ((size_t)g0 << 10) + ce;
  const uint16_t* Bg = B + ((size_t)g0 << 10) + ce;

  f32x4_t acc[8][4];
#pragma unroll
  for (int i = 0; i < 8; i++)
#pragma unroll
    for (int j = 0; j < 4; j++) acc[i][j] = (f32x4_t){0.f, 0.f, 0.f, 0.f};

  for (int k0 = 0; k0 < 1024; k0 += 64) {
    // A and B: 4 x 16B per thread each (rows g0+64s).
#pragma unroll
    for (int s = 0; s < 4; ++s)
      async_copy16(Ag + (((size_t)s << 6) << 10) + k0, As + so + (s << 13));
#pragma unroll
    for (int s = 0; s < 4; ++s)
      async_copy16(Bg + (((size_t)s << 6) << 10) + k0, Bs + so + (s << 13));
    __syncthreads();

#pragma unroll
    for (int kk = 0; kk < 2; ++kk) {
      bf16x8_t af[8], bfr[4];
#pragma unroll
      for (int mi = 0; mi < 8; ++mi) {
        const int m = wm + (mi << 4) + r16;
        const int c = (kk << 2) + q;
        af[mi] = *(const bf16x8_t*)(As + (m << 7) + ((c ^ (m & 7)) << 4));
      }
#pragma unroll
      for (int ni = 0; ni < 4; ++ni) {
        const int n = wn + (ni << 4) + r16;
        const int c = (kk << 2) + q;
        bfr[ni] = *(const bf16x8_t*)(Bs + (n << 7) + ((c ^ (n & 7)) << 4));
      }
      __builtin_amdgcn_s_setprio(1);
#pragma unroll
      for (int mi = 0; mi < 8; ++mi)
#pragma unroll
        for (int ni = 0; ni < 4; ++ni)
          acc[mi][ni] = __builtin_amdgcn_mfma_f32_16x16x32_bf16(
              af[mi], bfr[ni], acc[mi][ni], 0, 0, 0);
      __builtin_amdgcn_s_setprio(0);
    }
    __syncthreads();
  }

  // bf16 epilogue via per-wave-private LDS staging (8 x 1056 f32 = 33KB).
  float* reg = (float*)smem + (size_t)w * 1056;   // 16 x 66 floats
  uint16_t* C = Cg + (size_t)z * sC;
#pragma unroll
  for (int mi = 0; mi < 8; ++mi) {
#pragma unroll
    for (int ni = 0; ni < 4; ++ni)
#pragma unroll
      for (int r = 0; r < 4; ++r)
        reg[((q << 2) + r) * 66 + (ni << 4) + r16] = acc[mi][ni][r];
#pragma unroll
    for (int it = 0; it < 8; ++it) {
      const int rr = (it << 1) + (lane >> 5);     // 0..15
      const int cc = (lane & 31) << 1;            // 0..62
      const float2 v = *(const float2*)(reg + rr * 66 + cc);
      const uint32_t p = (uint32_t)f2bf(v.x) | ((uint32_t)f2bf(v.y) << 16);
      const int row = bm0 + wm + (mi << 4) + rr;
      const int col = bn0 + wn + cc;
      *(uint32_t*)(C + ((size_t)row << 10) + col) = p;
    }
  }
}

// Two independent bf16 gemms in one 512-block launch (256 + 256), 256^2 tile.
__global__ __launch_bounds__(512, 4)
void gemm_pair(const uint16_t* __restrict__ A0, const uint16_t* __restrict__ B0,
               uint16_t* __restrict__ C0, size_t sA0, size_t sB0, size_t sC0,
               const uint16_t* __restrict__ A1, const uint16_t* __restrict__ B1,
               uint16_t* __restrict__ C1, size_t sA1, size_t sB1, size_t sC1)
{
  __shared__ __align__(16) char smem[65536];
  const int lid = blockIdx.x;
  if (lid < 256)
    gemm_body256(A0, B0, C0, sA0, sB0, sC0, lid, smem);
  else
    gemm_body256(A1, B1, C1, sA1, sB1, sC1, lid - 256, smem);
}

// ONE prep dispatch (5376 blocks x 256 thr), all inputs raw d_in:
//   blocks    0..255  : W2T split-K partials (4 slices x 64 tiles, K=256),
//                       inline f32->bf16 reg staging from raw wq/wk.
//   blocks  256..4351 : xT transpose-cast (16 batches x 16x16 tiles of 64x64)
//   blocks 4352..5375 : Wtv = Wv^T cast (1024 tiles of 32x32)
__global__ __launch_bounds__(256)
void prep_all(const float* __restrict__ x, uint16_t* __restrict__ xT,
              const float* __restrict__ wq, const float* __restrict__ wk,
              const float* __restrict__ wv, float* __restrict__ W2p,
              uint16_t* __restrict__ Wtv)
{
  __shared__ __align__(16) char smem[32768];
  const int bx = blockIdx.x;
  const int t  = threadIdx.x;

  if (bx < 256) {
    char* As = smem;            // 128 x 64 bf16 = 16384 B
    char* Bs = smem + 16384;
    const int slice = bx >> 6;
    const int tile4 = bx & 63;
    const int bm0   = (tile4 >> 3) << 7;
    const int bn0   = (tile4 & 7) << 7;
    const int koff  = slice << 8;
    const int lane = t & 63;
    const int w4 = t >> 6;
    const int q = lane >> 4;
    const int r16 = lane & 15;
    const int wm = (w4 >> 1) << 6;
    const int wn = (w4 & 1) << 6;
    const int g0 = t >> 1;
    const int kh = (t & 1) << 5;
    const float* srcA = wq + (size_t)(bm0 + g0) * 1024 + kh;
    const float* srcB = wk + (size_t)(bn0 + g0) * 1024 + kh;

    f32x4_t acc[4][4];
#pragma unroll
    for (int i = 0; i < 4; i++)
#pragma unroll
      for (int j = 0; j < 4; j++) acc[i][j] = (f32x4_t){0.f, 0.f, 0.f, 0.f};

    for (int k0 = koff; k0 < koff + 256; k0 += 64) {
#pragma unroll
      for (int j = 0; j < 4; ++j) {      // chunk c = (t&1)*4 + j
        const int c  = ((t & 1) << 2) + j;
        const int cp = c ^ (g0 & 7);
        const float4 a0 = *(const float4*)(srcA + k0 + (j << 3));
        const float4 a1 = *(const float4*)(srcA + k0 + (j << 3) + 4);
        const float4 b0 = *(const float4*)(srcB + k0 + (j << 3));
        const float4 b1 = *(const float4*)(srcB + k0 + (j << 3) + 4);
        uint4 pa, pb;
        pa.x = (uint32_t)f2bf(a0.x) | ((uint32_t)f2bf(a0.y) << 16);
        pa.y = (uint32_t)f2bf(a0.z) | ((uint32_t)f2bf(a0.w) << 16);
        pa.z = (uint32_t)f2bf(a1.x) | ((uint32_t)f2bf(a1.y) << 16);
        pa.w = (uint32_t)f2bf(a1.z) | ((uint32_t)f2bf(a1.w) << 16);
        pb.x = (uint32_t)f2bf(b0.x) | ((uint32_t)f2bf(b0.y) << 16);
        pb.y = (uint32_t)f2bf(b0.z) | ((uint32_t)f2bf(b0.w) << 16);
        pb.z = (uint32_t)f2bf(b1.x) | ((uint32_t)f2bf(b1.y) << 16);
        pb.w = (uint32_t)f2bf(b1.z) | ((uint32_t)f2bf(b1.w) << 16);
        *(uint4*)(As + (g0 << 7) + (cp << 4)) = pa;
        *(uint4*)(Bs + (g0 << 7) + (cp << 4)) = pb;
      }
      __syncthreads();
#pragma unroll
      for (int kk = 0; kk < 2; kk++) {
        bf16x8_t af[4], bfr[4];
#pragma unroll
        for (int mi = 0; mi < 4; mi++) {
          const int m = wm + (mi << 4) + r16;
          const int c = (kk << 2) + q;
          af[mi] = *(const bf16x8_t*)(As + (m << 7) + ((c ^ (m & 7)) << 4));
        }
#pragma unroll
        for (int ni = 0; ni < 4; ni++) {
          const int n = wn + (ni << 4) + r16;
          const int c = (kk << 2) + q;
          bfr[ni] = *(const bf16x8_t*)(Bs + (n << 7) + ((c ^ (n & 7)) << 4));
        }
#pragma unroll
        for (int mi = 0; mi < 4; mi++)
#pragma unroll
          for (int ni = 0; ni < 4; ni++)
            acc[mi][ni] = __builtin_amdgcn_mfma_f32_16x16x32_bf16(
                af[mi], bfr[ni], acc[mi][ni], 0, 0, 0);
      }
      __syncthreads();
    }
    float* C = W2p + (size_t)slice * (1024u * 1024u);
#pragma unroll
    for (int mi = 0; mi < 4; mi++)
#pragma unroll
      for (int ni = 0; ni < 4; ni++)
#pragma unroll
        for (int r = 0; r < 4; r++) {
          const int row = bm0 + wm + (mi << 4) + (q << 2) + r;
          const int col = bn0 + wn + (ni << 4) + r16;
          C[((size_t)row << 10) + col] = acc[mi][ni][r];
        }
    return;
  }

  if (bx < 4352) {
    // ---- xT transpose-cast: dst[c][r] = bf16(src[r][c]), 64x64 tile ----
    float (*tile)[65] = (float(*)[65])smem;   // 64 x 65 f32 = 16640 B
    const int bxx = bx - 256;
    const int z  = bxx >> 8;
    const int r0 = ((bxx >> 4) & 15) << 6;
    const int c0 = (bxx & 15) << 6;
    const float* src = x + ((size_t)z << 20);
    uint16_t* dst = xT + ((size_t)z << 20);
    const int row  = t >> 4;              // 0..15
    const int col4 = (t & 15) << 2;       // 0,4,...,60
#pragma unroll
    for (int i = 0; i < 4; ++i) {
      const float4 v = *(const float4*)(
          src + (size_t)(r0 + row + (i << 4)) * 1024 + c0 + col4);
      float* tp = &tile[row + (i << 4)][col4];
      tp[0] = v.x; tp[1] = v.y; tp[2] = v.z; tp[3] = v.w;
    }
    __syncthreads();
#pragma unroll
    for (int p = 0; p < 2; ++p) {
      const int idx = (p << 8) + t;
      const int c  = idx >> 3;            // 0..63
      const int s8 = (idx & 7) << 3;      // 0,8,...,56
      uint32_t u0 = (uint32_t)f2bf(tile[s8 + 0][c]) |
                    ((uint32_t)f2bf(tile[s8 + 1][c]) << 16);
      uint32_t u1 = (uint32_t)f2bf(tile[s8 + 2][c]) |
                    ((uint32_t)f2bf(tile[s8 + 3][c]) << 16);
      uint32_t u2 = (uint32_t)f2bf(tile[s8 + 4][c]) |
                    ((uint32_t)f2bf(tile[s8 + 5][c]) << 16);
      uint32_t u3 = (uint32_t)f2bf(tile[s8 + 6][c]) |
                    ((uint32_t)f2bf(tile[s8 + 7][c]) << 16);
      uint4 pk; pk.x = u0; pk.y = u1; pk.z = u2; pk.w = u3;
      *(uint4*)(dst + (size_t)(c0 + c) * 1024 + r0 + s8) = pk;
    }
    return;
  }

  // ---- Wtv transpose-cast: Wtv[c][r] = bf16(wv[r][c]), 32x32 tiles ----
  {
    float (*tile)[33] = (float(*)[33])smem;
    const int bxw = bx - 4352;            // 0..1023
    const int r0 = (bxw >> 5) << 5;
    const int c0 = (bxw & 31) << 5;
    const int tx = t & 31, ty = t >> 5;   // (32,8)
#pragma unroll
    for (int i = 0; i < 32; i += 8)
      tile[ty + i][tx] = wv[(size_t)(r0 + ty + i) * 1024 + (c0 + tx)];
    __syncthreads();
#pragma unroll
    for (int i = 0; i < 32; i += 8)
      Wtv[(size_t)(c0 + ty + i) * 1024 + (r0 + tx)] = f2bf(tile[tx][ty + i]);
  }
}

// W2Tc = bf16( P[0] + P[1] + P[2] + P[3] ).  grid 1024 x 256thr, 4 elems/thr.
__global__ __launch_bounds__(256)
void reduce_w2t(const float* __restrict__ P, uint16_t* __restrict__ W)
{
  const size_t i4 = (((size_t)blockIdx.x << 8) + threadIdx.x) << 2;
  const float4 a = *(const float4*)(P + i4);
  const float4 b = *(const float4*)(P + (1u << 20) + i4);
  const float4 c = *(const float4*)(P + (2u << 20) + i4);
  const float4 d = *(const float4*)(P + (3u << 20) + i4);
  ushort4 r;
  r.x = f2bf(a.x + b.x + c.x + d.x);
  r.y = f2bf(a.y + b.y + c.y + d.y);
  r.z = f2bf(a.z + b.z + c.z + d.z);
  r.w = f2bf(a.w + b.w + c.w + d.w);
  *(ushort4*)(W + i4) = r;
}

extern "C" void kernel_launch(void* const* d_in, const int* in_sizes, int n_in,
                              void* d_out, int out_size, void* d_ws, size_t ws_size,
                              hipStream_t stream)
{
  const float* x  = (const float*)d_in[0];
  const float* wk = (const float*)d_in[1];
  const float* wq = (const float*)d_in[2];
  const float* wv = (const float*)d_in[3];
  float* out = (float*)d_out;

  constexpr int N = 1024;
  constexpr size_t DN = (size_t)N * N;

  // workspace layout (bytes)           size    lifetime
  // xT    @ 0                          32 MB   through P gemm
  // Wtv   @ 36M                         2 MB
  // W2Tc  @ 38M                         2 MB   dead after pair
  // W2p   @ 40M                        16 MB   dead after reduce
  // tmp   @ 56M                        32 MB   dead after P gemm
  // vvT   @ 88M                        32 MB
  // P(kq) @ 120M                       32 MB   exp(kq/32), bf16
  // Spart @ 152M                        1 MB   16 slots x 16 x 1024 f32
  char* ws = (char*)d_ws;
  uint16_t* xT   = (uint16_t*)(ws);
  uint16_t* Wtv  = (uint16_t*)(ws + (36ull << 20));
  uint16_t* W2Tc = (uint16_t*)(ws + (38ull << 20));
  float*    W2p  = (float*)   (ws + (40ull << 20));
  uint16_t* tmp  = (uint16_t*)(ws + (56ull << 20));
  uint16_t* vvT  = (uint16_t*)(ws + (88ull << 20));
  uint16_t* P    = (uint16_t*)(ws + (120ull << 20));
  float*    Spart= (float*)   (ws + (152ull << 20));

  // ONE prep dispatch: W2T splitk partials (inline cast, 4 slices) +
  // xT transpose + Wv transpose.
  prep_all<<<5376, 256, 0, stream>>>(x, xT, wq, wk, wv, W2p, Wtv);
  reduce_w2t<<<1024, 256, 0, stream>>>(W2p, W2Tc);
  // Merged independent pair (both consume xT only), 256^2 tile:
  //   job0: tmp[b][d][j] = sum_i xT[b][d][i] * W2T[j][i]
  //   job1: vvT[b][n][d] = sum_n' Wtv[n][n'] * xT[b][d][n']
  gemm_pair<<<512, 512, 0, stream>>>(xT, W2Tc, tmp, DN, 0, DN,
                                     Wtv, xT, vvT, 0, DN, DN);
  // P[b][d][e] = exp( (1/32) sum_j tmp[b][d][j] * xT[b][e][j] ),  + Spart
  gemm_bt256x128<2><<<512, 512, 0, stream>>>(tmp, xT, P, DN, DN, DN, 0.03125f, Spart);
  // out[b][n][d] = ( sum_e vvT[b][n][e] * P[b][d][e] ) / S[b][d]
  gemm_bt256x128<3><<<512, 512, 0, stream>>>(vvT, P, out, DN, DN, DN, 1.0f, Spart);
}

// Round 14
// 276.053 us; speedup vs baseline: 3.0819x; 3.0819x over previous
//
#include <hip/hip_runtime.h>
#include <stdint.h>

// ---------------------------------------------------------------------------
// SelfAttention: out[b,n,d] = ( softmax( (X^T Wk)(X^T Wq)^T / 32 ) (X^T Wv) )^T
// B=16, N=D=1024.
//
// R5 algebra: kq = xT (Wk Wq^T) x -> 4 big GEMMs (tmp, vvT, kq(P), out).
// R6a fusion: softmax folded into GEMM epilogues (EPI=2 exp+Spart, EPI=3 /S).
// R7 gemm (plateau): 256x128 tile, BK=64, 512thr/8 waves, 48KiB LDS;
//   LDS-pipe-bound; co-residency is the only paying lever.
// R11: tmp+vvT merged -> 1024-block gemm_pair (3 blocks/CU).  -14 us.
// R14 (BEST, 276.2 us): prep consolidated (splitk 4-slice inline-cast +
//   transposes in ONE dispatch) + reduce fixup.
// R15 (P/out producer-consumer): regressed -26 us (sleeping consumers hold
//   residency).  R16 (256^2 pair): regressed -574 us (launch_bounds(512,4)
//   caps 128 VGPR < acc[8][4]'s ~200 -> scratch spill, 3.3GB/dispatch).
// R17 (this): exact revert to R14.  All axes explored and bounded; this is
//   the verified best configuration.
// ---------------------------------------------------------------------------

typedef __bf16 bf16x8_t __attribute__((ext_vector_type(8)));
typedef float  f32x4_t  __attribute__((ext_vector_type(4)));

typedef __attribute__((address_space(3))) uint32_t as3_u32;
typedef __attribute__((address_space(1))) uint32_t as1_u32;

__device__ __forceinline__ void async_copy16(const void* g, const void* l) {
  __builtin_amdgcn_global_load_lds((const as1_u32*)(uintptr_t)g,
                                   (as3_u32*)(uint32_t)(uintptr_t)l,
                                   16, 0, 0);
}

__device__ __forceinline__ uint16_t f2bf(float f) {  // RNE
  uint32_t x = __float_as_uint(f);
  return (uint16_t)((x + 0x7fffu + ((x >> 16) & 1u)) >> 16);
}
__device__ __forceinline__ float bf2f(uint16_t b) {
  return __uint_as_float(((uint32_t)b) << 16);
}

// C[m,n] = alpha * sum_k A[m,k] * B[n,k].  M=N=K=1024 fixed per batch slice.
// Tile 256(M) x 128(N), BK=64.  512 logical blocks x 512 threads.
// EPI: 0 = bf16 C*alpha;  2 = bf16 exp(C*alpha) + Spart row partials;
//      3 = f32 C*alpha/S[col] (S = sum of 16 Spart slots).
template <int EPI>
__device__ __forceinline__ void gemm_body(
    const uint16_t* __restrict__ A, const uint16_t* __restrict__ B,
    void* __restrict__ Cv, size_t sA, size_t sB, size_t sC,
    float alpha, float* __restrict__ Sp, int lid, char* smem)
{
  char* As = smem;            // 256 x 64 bf16 = 32768 B
  char* Bs = smem + 32768;    // 128 x 64 bf16 = 16384 B

  // ---- XCD swizzle: lid%8 = XCD; 2 batches per XCD, 4x8 tiles per batch ----
  const int xcd  = lid & 7;
  const int slot = lid >> 3;            // 0..63
  const int z    = (xcd << 1) | (slot >> 5);
  const int t32  = slot & 31;
  const int bm0  = (t32 >> 3) << 8;     // 0,256,512,768
  const int bn0  = (t32 & 7) << 7;      // 0..896 step 128

  A += (size_t)z * sA + ((size_t)bm0 << 10);
  B += (size_t)z * sB + ((size_t)bn0 << 10);

  const int t    = threadIdx.x;
  const int lane = t & 63;
  const int w    = t >> 6;              // 0..7
  const int q    = lane >> 4;
  const int r16  = lane & 15;
  const int wm   = (w >> 1) << 6;       // 0,64,128,192
  const int wn   = (w & 1) << 6;        // 0,64

  // ---- staging constants: row pitch 128 B, slot cp holds chunk cp^(row&7) --
  const int g0  = t >> 3;               // 0..63
  const int cp  = t & 7;
  const int ce  = (cp ^ (g0 & 7)) << 3; // (g0+64s)&7 == g0&7, so ce is const
  const int so  = (g0 << 7) + (cp << 4);
  const uint16_t* Ag = A + ((size_t)g0 << 10) + ce;
  const uint16_t* Bg = B + ((size_t)g0 << 10) + ce;

  f32x4_t acc[4][4];
#pragma unroll
  for (int i = 0; i < 4; i++)
#pragma unroll
    for (int j = 0; j < 4; j++) acc[i][j] = (f32x4_t){0.f, 0.f, 0.f, 0.f};

  for (int k0 = 0; k0 < 1024; k0 += 64) {
    // A: 4 x 16B per thread (rows g0+64s); B: 2 x 16B (rows g0+64s).
#pragma unroll
    for (int s = 0; s < 4; ++s)
      async_copy16(Ag + (((size_t)s << 6) << 10) + k0, As + so + (s << 13));
#pragma unroll
    for (int s = 0; s < 2; ++s)
      async_copy16(Bg + (((size_t)s << 6) << 10) + k0, Bs + so + (s << 13));
    __syncthreads();   // full drain (vmcnt 0); hidden by co-resident blocks

#pragma unroll
    for (int kk = 0; kk < 2; ++kk) {
      bf16x8_t af[4], bfr[4];
#pragma unroll
      for (int mi = 0; mi < 4; ++mi) {
        const int m = wm + (mi << 4) + r16;
        const int c = (kk << 2) + q;
        af[mi] = *(const bf16x8_t*)(As + (m << 7) + ((c ^ (m & 7)) << 4));
      }
#pragma unroll
      for (int ni = 0; ni < 4; ++ni) {
        const int n = wn + (ni << 4) + r16;
        const int c = (kk << 2) + q;
        bfr[ni] = *(const bf16x8_t*)(Bs + (n << 7) + ((c ^ (n & 7)) << 4));
      }
      __builtin_amdgcn_s_setprio(1);
#pragma unroll
      for (int mi = 0; mi < 4; ++mi)
#pragma unroll
        for (int ni = 0; ni < 4; ++ni)
          acc[mi][ni] = __builtin_amdgcn_mfma_f32_16x16x32_bf16(
              af[mi], bfr[ni], acc[mi][ni], 0, 0, 0);
      __builtin_amdgcn_s_setprio(0);
    }
    __syncthreads();
  }

  // ---- epilogue.  C/D layout: col=lane&15, row=q*4+r (verified m89/m91) ----
  if constexpr (EPI == 3) {
    // f32 out, scaled by 1/S[col]; S = sum of 16 Spart slots per column.
    float inv[4];
#pragma unroll
    for (int ni = 0; ni < 4; ++ni) {
      const int c = bn0 + wn + (ni << 4) + r16;
      float S = 0.f;
#pragma unroll
      for (int p = 0; p < 16; ++p)
        S += Sp[((size_t)p << 14) + ((size_t)z << 10) + c];
      inv[ni] = 1.0f / S;
    }
    float* C = (float*)Cv + (size_t)z * sC;
#pragma unroll
    for (int mi = 0; mi < 4; ++mi)
#pragma unroll
      for (int ni = 0; ni < 4; ++ni)
#pragma unroll
        for (int r = 0; r < 4; ++r) {
          const int row = bm0 + wm + (mi << 4) + (q << 2) + r;
          const int col = bn0 + wn + (ni << 4) + r16;
          C[((size_t)row << 10) + col] = acc[mi][ni][r] * alpha * inv[ni];
        }
  } else {
    // bf16 out via per-wave-private LDS staging -> full 128-B row stores.
    // EPI==2 additionally applies exp() and emits per-row partial sums.
    float* reg = (float*)smem + (size_t)w * 1056;   // 16 x 66 floats
    uint16_t* C = (uint16_t*)Cv + (size_t)z * sC;
    float* SpW = Sp + ((size_t)(((bn0 >> 7) << 1) + (w & 1)) << 14)
                    + ((size_t)z << 10);
#pragma unroll
    for (int mi = 0; mi < 4; ++mi) {
      if constexpr (EPI == 2) {
        float ev[4][4];
#pragma unroll
        for (int ni = 0; ni < 4; ++ni)
#pragma unroll
          for (int r = 0; r < 4; ++r) {
            ev[ni][r] = __expf(acc[mi][ni][r] * alpha);
            reg[((q << 2) + r) * 66 + (ni << 4) + r16] = ev[ni][r];
          }
#pragma unroll
        for (int r = 0; r < 4; ++r) {
          float s = ev[0][r] + ev[1][r] + ev[2][r] + ev[3][r];
          s += __shfl_xor(s, 1, 16);
          s += __shfl_xor(s, 2, 16);
          s += __shfl_xor(s, 4, 16);
          s += __shfl_xor(s, 8, 16);
          if (r16 == 0)
            SpW[bm0 + wm + (mi << 4) + (q << 2) + r] = s;
        }
      } else {
#pragma unroll
        for (int ni = 0; ni < 4; ++ni)
#pragma unroll
          for (int r = 0; r < 4; ++r)
            reg[((q << 2) + r) * 66 + (ni << 4) + r16] = acc[mi][ni][r] * alpha;
      }
#pragma unroll
      for (int it = 0; it < 8; ++it) {
        const int rr = (it << 1) + (lane >> 5);     // 0..15
        const int cc = (lane & 31) << 1;            // 0..62
        const float2 v = *(const float2*)(reg + rr * 66 + cc);
        const uint32_t p = (uint32_t)f2bf(v.x) | ((uint32_t)f2bf(v.y) << 16);
        const int row = bm0 + wm + (mi << 4) + rr;
        const int col = bn0 + wn + cc;
        *(uint32_t*)(C + ((size_t)row << 10) + col) = p;
      }
    }
  }
}

template <int EPI>
__global__ __launch_bounds__(512, 4)
void gemm_bt256x128(const uint16_t* __restrict__ A,
                    const uint16_t* __restrict__ B,
                    void* __restrict__ Cv, size_t sA, size_t sB, size_t sC,
                    float alpha, float* __restrict__ Sp)
{
  __shared__ __align__(16) char smem[49152];
  gemm_body<EPI>(A, B, Cv, sA, sB, sC, alpha, Sp, blockIdx.x, smem);
}

// Two independent EPI=0 gemms in one 1024-block launch (blocks 0-511 -> job0,
// 512-1023 -> job1).  48KB LDS -> 3 blocks/CU co-resident (vs 2 grid-limited).
__global__ __launch_bounds__(512, 4)
void gemm_pair(const uint16_t* __restrict__ A0, const uint16_t* __restrict__ B0,
               void* __restrict__ C0, size_t sA0, size_t sB0, size_t sC0,
               const uint16_t* __restrict__ A1, const uint16_t* __restrict__ B1,
               void* __restrict__ C1, size_t sA1, size_t sB1, size_t sC1)
{
  __shared__ __align__(16) char smem[49152];
  const int lid = blockIdx.x;
  if (lid < 512)
    gemm_body<0>(A0, B0, C0, sA0, sB0, sC0, 1.0f, nullptr, lid, smem);
  else
    gemm_body<0>(A1, B1, C1, sA1, sB1, sC1, 1.0f, nullptr, lid - 512, smem);
}

// ONE prep dispatch (5376 blocks x 256 thr), all inputs raw d_in:
//   blocks    0..255  : W2T split-K partials (4 slices x 64 tiles, K=256),
//                       inline f32->bf16 reg staging from raw wq/wk.
//   blocks  256..4351 : xT transpose-cast (16 batches x 16x16 tiles of 64x64)
//   blocks 4352..5375 : Wtv = Wv^T cast (1024 tiles of 32x32)
__global__ __launch_bounds__(256)
void prep_all(const float* __restrict__ x, uint16_t* __restrict__ xT,
              const float* __restrict__ wq, const float* __restrict__ wk,
              const float* __restrict__ wv, float* __restrict__ W2p,
              uint16_t* __restrict__ Wtv)
{
  __shared__ __align__(16) char smem[32768];
  const int bx = blockIdx.x;
  const int t  = threadIdx.x;

  if (bx < 256) {
    // ---- W2p[s][j,i] = sum_{n in slice s} Wq[j,n] Wk[i,n]; inline cast ----
    char* As = smem;            // 128 x 64 bf16 = 16384 B
    char* Bs = smem + 16384;
    const int slice = bx >> 6;
    const int tile4 = bx & 63;
    const int bm0   = (tile4 >> 3) << 7;
    const int bn0   = (tile4 & 7) << 7;
    const int koff  = slice << 8;
    const int lane = t & 63;
    const int w4 = t >> 6;
    const int q = lane >> 4;
    const int r16 = lane & 15;
    const int wm = (w4 >> 1) << 6;
    const int wn = (w4 & 1) << 6;
    // staging: thread t -> row g0 = t>>1 (0..127), k-half kh = (t&1)*32
    const int g0 = t >> 1;
    const int kh = (t & 1) << 5;
    const float* srcA = wq + (size_t)(bm0 + g0) * 1024 + kh;
    const float* srcB = wk + (size_t)(bn0 + g0) * 1024 + kh;

    f32x4_t acc[4][4];
#pragma unroll
    for (int i = 0; i < 4; i++)
#pragma unroll
      for (int j = 0; j < 4; j++) acc[i][j] = (f32x4_t){0.f, 0.f, 0.f, 0.f};

    for (int k0 = koff; k0 < koff + 256; k0 += 64) {
#pragma unroll
      for (int j = 0; j < 4; ++j) {      // chunk c = (t&1)*4 + j
        const int c  = ((t & 1) << 2) + j;
        const int cp = c ^ (g0 & 7);
        const float4 a0 = *(const float4*)(srcA + k0 + (j << 3));
        const float4 a1 = *(const float4*)(srcA + k0 + (j << 3) + 4);
        const float4 b0 = *(const float4*)(srcB + k0 + (j << 3));
        const float4 b1 = *(const float4*)(srcB + k0 + (j << 3) + 4);
        uint4 pa, pb;
        pa.x = (uint32_t)f2bf(a0.x) | ((uint32_t)f2bf(a0.y) << 16);
        pa.y = (uint32_t)f2bf(a0.z) | ((uint32_t)f2bf(a0.w) << 16);
        pa.z = (uint32_t)f2bf(a1.x) | ((uint32_t)f2bf(a1.y) << 16);
        pa.w = (uint32_t)f2bf(a1.z) | ((uint32_t)f2bf(a1.w) << 16);
        pb.x = (uint32_t)f2bf(b0.x) | ((uint32_t)f2bf(b0.y) << 16);
        pb.y = (uint32_t)f2bf(b0.z) | ((uint32_t)f2bf(b0.w) << 16);
        pb.z = (uint32_t)f2bf(b1.x) | ((uint32_t)f2bf(b1.y) << 16);
        pb.w = (uint32_t)f2bf(b1.z) | ((uint32_t)f2bf(b1.w) << 16);
        *(uint4*)(As + (g0 << 7) + (cp << 4)) = pa;
        *(uint4*)(Bs + (g0 << 7) + (cp << 4)) = pb;
      }
      __syncthreads();
#pragma unroll
      for (int kk = 0; kk < 2; kk++) {
        bf16x8_t af[4], bfr[4];
#pragma unroll
        for (int mi = 0; mi < 4; mi++) {
          const int m = wm + (mi << 4) + r16;
          const int c = (kk << 2) + q;
          af[mi] = *(const bf16x8_t*)(As + (m << 7) + ((c ^ (m & 7)) << 4));
        }
#pragma unroll
        for (int ni = 0; ni < 4; ni++) {
          const int n = wn + (ni << 4) + r16;
          const int c = (kk << 2) + q;
          bfr[ni] = *(const bf16x8_t*)(Bs + (n << 7) + ((c ^ (n & 7)) << 4));
        }
#pragma unroll
        for (int mi = 0; mi < 4; mi++)
#pragma unroll
          for (int ni = 0; ni < 4; ni++)
            acc[mi][ni] = __builtin_amdgcn_mfma_f32_16x16x32_bf16(
                af[mi], bfr[ni], acc[mi][ni], 0, 0, 0);
      }
      __syncthreads();
    }
    float* C = W2p + (size_t)slice * (1024u * 1024u);
#pragma unroll
    for (int mi = 0; mi < 4; mi++)
#pragma unroll
      for (int ni = 0; ni < 4; ni++)
#pragma unroll
        for (int r = 0; r < 4; r++) {
          const int row = bm0 + wm + (mi << 4) + (q << 2) + r;
          const int col = bn0 + wn + (ni << 4) + r16;
          C[((size_t)row << 10) + col] = acc[mi][ni][r];
        }
    return;
  }

  if (bx < 4352) {
    // ---- xT transpose-cast: dst[c][r] = bf16(src[r][c]), 64x64 tile ----
    float (*tile)[65] = (float(*)[65])smem;   // 64 x 65 f32 = 16640 B
    const int bxx = bx - 256;
    const int z  = bxx >> 8;
    const int r0 = ((bxx >> 4) & 15) << 6;
    const int c0 = (bxx & 15) << 6;
    const float* src = x + ((size_t)z << 20);
    uint16_t* dst = xT + ((size_t)z << 20);
    const int row  = t >> 4;              // 0..15
    const int col4 = (t & 15) << 2;       // 0,4,...,60
#pragma unroll
    for (int i = 0; i < 4; ++i) {
      const float4 v = *(const float4*)(
          src + (size_t)(r0 + row + (i << 4)) * 1024 + c0 + col4);
      float* tp = &tile[row + (i << 4)][col4];
      tp[0] = v.x; tp[1] = v.y; tp[2] = v.z; tp[3] = v.w;
    }
    __syncthreads();
#pragma unroll
    for (int p = 0; p < 2; ++p) {
      const int idx = (p << 8) + t;
      const int c  = idx >> 3;            // 0..63
      const int s8 = (idx & 7) << 3;      // 0,8,...,56
      uint32_t u0 = (uint32_t)f2bf(tile[s8 + 0][c]) |
                    ((uint32_t)f2bf(tile[s8 + 1][c]) << 16);
      uint32_t u1 = (uint32_t)f2bf(tile[s8 + 2][c]) |
                    ((uint32_t)f2bf(tile[s8 + 3][c]) << 16);
      uint32_t u2 = (uint32_t)f2bf(tile[s8 + 4][c]) |
                    ((uint32_t)f2bf(tile[s8 + 5][c]) << 16);
      uint32_t u3 = (uint32_t)f2bf(tile[s8 + 6][c]) |
                    ((uint32_t)f2bf(tile[s8 + 7][c]) << 16);
      uint4 pk; pk.x = u0; pk.y = u1; pk.z = u2; pk.w = u3;
      *(uint4*)(dst + (size_t)(c0 + c) * 1024 + r0 + s8) = pk;
    }
    return;
  }

  // ---- Wtv transpose-cast: Wtv[c][r] = bf16(wv[r][c]), 32x32 tiles ----
  {
    float (*tile)[33] = (float(*)[33])smem;
    const int bxw = bx - 4352;            // 0..1023
    const int r0 = (bxw >> 5) << 5;
    const int c0 = (bxw & 31) << 5;
    const int tx = t & 31, ty = t >> 5;   // (32,8)
#pragma unroll
    for (int i = 0; i < 32; i += 8)
      tile[ty + i][tx] = wv[(size_t)(r0 + ty + i) * 1024 + (c0 + tx)];
    __syncthreads();
#pragma unroll
    for (int i = 0; i < 32; i += 8)
      Wtv[(size_t)(c0 + ty + i) * 1024 + (r0 + tx)] = f2bf(tile[tx][ty + i]);
  }
}

// W2Tc = bf16( P[0] + P[1] + P[2] + P[3] ).  grid 1024 x 256thr, 4 elems/thr.
__global__ __launch_bounds__(256)
void reduce_w2t(const float* __restrict__ P, uint16_t* __restrict__ W)
{
  const size_t i4 = (((size_t)blockIdx.x << 8) + threadIdx.x) << 2;
  const float4 a = *(const float4*)(P + i4);
  const float4 b = *(const float4*)(P + (1u << 20) + i4);
  const float4 c = *(const float4*)(P + (2u << 20) + i4);
  const float4 d = *(const float4*)(P + (3u << 20) + i4);
  ushort4 r;
  r.x = f2bf(a.x + b.x + c.x + d.x);
  r.y = f2bf(a.y + b.y + c.y + d.y);
  r.z = f2bf(a.z + b.z + c.z + d.z);
  r.w = f2bf(a.w + b.w + c.w + d.w);
  *(ushort4*)(W + i4) = r;
}

extern "C" void kernel_launch(void* const* d_in, const int* in_sizes, int n_in,
                              void* d_out, int out_size, void* d_ws, size_t ws_size,
                              hipStream_t stream)
{
  const float* x  = (const float*)d_in[0];
  const float* wk = (const float*)d_in[1];
  const float* wq = (const float*)d_in[2];
  const float* wv = (const float*)d_in[3];
  float* out = (float*)d_out;

  constexpr int N = 1024;
  constexpr size_t DN = (size_t)N * N;

  // workspace layout (bytes)           size    lifetime
  // xT    @ 0                          32 MB   through P gemm
  // Wtv   @ 36M                         2 MB
  // W2Tc  @ 38M                         2 MB   dead after pair
  // W2p   @ 40M                        16 MB   dead after reduce
  // tmp   @ 56M                        32 MB   dead after P gemm
  // vvT   @ 88M                        32 MB
  // P(kq) @ 120M                       32 MB   exp(kq/32), bf16
  // Spart @ 152M                        1 MB   16 slots x 16 x 1024 f32
  char* ws = (char*)d_ws;
  uint16_t* xT   = (uint16_t*)(ws);
  uint16_t* Wtv  = (uint16_t*)(ws + (36ull << 20));
  uint16_t* W2Tc = (uint16_t*)(ws + (38ull << 20));
  float*    W2p  = (float*)   (ws + (40ull << 20));
  uint16_t* tmp  = (uint16_t*)(ws + (56ull << 20));
  uint16_t* vvT  = (uint16_t*)(ws + (88ull << 20));
  uint16_t* P    = (uint16_t*)(ws + (120ull << 20));
  float*    Spart= (float*)   (ws + (152ull << 20));

  // ONE prep dispatch: W2T splitk partials (inline cast, 4 slices) +
  // xT transpose + Wv transpose.
  prep_all<<<5376, 256, 0, stream>>>(x, xT, wq, wk, wv, W2p, Wtv);
  reduce_w2t<<<1024, 256, 0, stream>>>(W2p, W2Tc);
  // Merged independent pair (both consume xT only):
  //   job0: tmp[b][d][j] = sum_i xT[b][d][i] * W2T[j][i]
  //   job1: vvT[b][n][d] = sum_n' Wtv[n][n'] * xT[b][d][n']
  gemm_pair<<<1024, 512, 0, stream>>>(xT, W2Tc, tmp, DN, 0, DN,
                                      Wtv, xT, vvT, 0, DN, DN);
  // P[b][d][e] = exp( (1/32) sum_j tmp[b][d][j] * xT[b][e][j] ),  + Spart
  gemm_bt256x128<2><<<512, 512, 0, stream>>>(tmp, xT, P, DN, DN, DN, 0.03125f, Spart);
  // out[b][n][d] = ( sum_e vvT[b][n][e] * P[b][d][e] ) / S[b][d]
  gemm_bt256x128<3><<<512, 512, 0, stream>>>(vvT, P, out, DN, DN, DN, 1.0f, Spart);
}